// Round 5
// baseline (1138.708 us; speedup 1.0000x reference)
//
#include <hip/hip_runtime.h>
#include <hip/hip_bf16.h>

#define B_   64
#define C_   512
#define N_   1024
#define NROW (B_ * C_)        // 32768 rows per tensor
#define BM   128
#define BK   128              // fp8 K-tile (one 16x16x128 MFMA deep)
#define NJOBS 36              // 10 tt + 10 ss + 16 ts tiles per batch
#define NGRAM (B_ * NJOBS)    // 2304 gram jobs
#define RN_JOBS 2048          // rownorm jobs, 32 rows each
#define TOTAL_JOBS (RN_JOBS + NGRAM)
#define ROWS_PER_WAVE 8
#define NBLOCKS 1280          // 5 blocks/CU x 256 CU

typedef __attribute__((ext_vector_type(8))) int   i32x8;
typedef __attribute__((ext_vector_type(4))) float f32x4;

__device__ __forceinline__ float wave_reduce(float v) {
  #pragma unroll
  for (int o = 32; o > 0; o >>= 1) v += __shfl_down(v, o, 64);
  return v;
}

__device__ __forceinline__ void load_row(const float* __restrict__ p, int lane,
                                         float4 v[4]) {
  #pragma unroll
  for (int j = 0; j < 4; ++j)
    v[j] = *(const float4*)(p + j * 256 + lane * 4);
}

__device__ __forceinline__ void proc_row(const float4 v[4],
                                         unsigned char* __restrict__ dst,
                                         int lane) {
  float ss = 0.0f;
  #pragma unroll
  for (int j = 0; j < 4; ++j)
    ss += v[j].x * v[j].x + v[j].y * v[j].y + v[j].z * v[j].z + v[j].w * v[j].w;
  #pragma unroll
  for (int o = 1; o < 64; o <<= 1) ss += __shfl_xor(ss, o, 64);
  // x16 scale keeps values in e4m3 normal range; removed exactly (2^-40 total)
  const float inv = 16.0f / fmaxf(sqrtf(ss), 1e-12f);
  #pragma unroll
  for (int j = 0; j < 4; ++j) {
    int p = __builtin_amdgcn_cvt_pk_fp8_f32(v[j].x * inv, v[j].y * inv, 0, false);
    p = __builtin_amdgcn_cvt_pk_fp8_f32(v[j].z * inv, v[j].w * inv, p, true);
    ((int*)(dst + j * 256))[lane] = p;
  }
}

// ctrl layout: [0]=job counter  [1]=gram-done counter  [2..65]=per-batch done
__global__ void zero_ctrl(int* ctrl) {
  if (threadIdx.x < 66) ctrl[threadIdx.x] = 0;
}

// ---------------- Fused persistent producer-consumer kernel -----------------
// jobs 0..2047          : rownorm (batch-major: job j -> batch j/32)
// jobs 2048..4351       : gram tiles (spin on per-batch done flag)
// job 4352              : final reduce (spin on gram-done == NGRAM)
__global__ __launch_bounds__(256, 5) void fused_nst(
    const float* __restrict__ fmt, const float* __restrict__ fms,
    unsigned char* __restrict__ nt, unsigned char* __restrict__ ns,
    float* __restrict__ partials, int* __restrict__ ctrl,
    float* __restrict__ out)
{
  __shared__ __align__(64) unsigned char As[BM * BK];
  __shared__ __align__(64) unsigned char Bs[BM * BK];
  // alias scratch into As (dead at job-grab / epilogue times; syncs protect)
  int*   s_job = (int*)As;
  float* red   = (float*)(As + 16);

  const int tid  = threadIdx.x;
  const int lane = tid & 63;
  const int wave = tid >> 6;

  for (;;) {
    __syncthreads();                       // prior job fully done with As alias
    if (tid == 0) *s_job = atomicAdd(&ctrl[0], 1);
    __syncthreads();
    const int job = *s_job;
    __syncthreads();                       // everyone has read s_job

    if (job < RN_JOBS) {
      // ---------------- rownorm job: 32 contiguous rows, 8 per wave --------
      const int b   = job >> 5;            // batch (jobs batch-major)
      const int k   = job & 31;
      const int arr = k >> 4;              // 0 -> t, 1 -> s
      const int r0  = b * C_ + (k & 15) * 32 + wave * ROWS_PER_WAVE;
      const float* src = (arr ? fms : fmt) + (size_t)r0 * N_;
      unsigned char* dst = (arr ? ns : nt) + (size_t)r0 * N_;

      float4 va[4], vb[4];
      load_row(src, lane, va);
      #pragma unroll
      for (int r = 0; r < ROWS_PER_WAVE; r += 2) {
        if (r + 1 < ROWS_PER_WAVE) load_row(src + (size_t)(r + 1) * N_, lane, vb);
        proc_row(va, dst + (size_t)r * N_, lane);
        if (r + 2 < ROWS_PER_WAVE) load_row(src + (size_t)(r + 2) * N_, lane, va);
        if (r + 1 < ROWS_PER_WAVE) proc_row(vb, dst + (size_t)(r + 1) * N_, lane);
      }
      __threadfence();                     // every thread: stores device-visible
      __syncthreads();
      if (tid == 0) atomicAdd(&ctrl[2 + b], 1);   // release per-batch counter

    } else if (job < TOTAL_JOBS) {
      // ---------------- gram tile job --------------------------------------
      const int gjob = job - RN_JOBS;
      const int b  = gjob / NJOBS;
      const int jb = gjob - b * NJOBS;

      int gi, gj;
      float wgt;
      int selA, selB;                      // 0 = t, 1 = s
      if (jb < 20) {
        const int idx = (jb < 10) ? jb : jb - 10;
        int i = 0, t = idx;
        while (t >= 4 - i) { t -= 4 - i; ++i; }
        gi = i; gj = i + t;
        wgt = (gi == gj) ? 1.0f : 2.0f;
        selA = selB = (jb < 10) ? 0 : 1;
      } else {
        const int idx = jb - 20;
        gi = idx >> 2; gj = idx & 3;
        wgt = -2.0f;
        selA = 0; selB = 1;
      }

      // wait until batch b's 32 rownorm jobs are done (acquire -> L1/L2 inv)
      if (tid == 0) {
        while (__hip_atomic_load(&ctrl[2 + b], __ATOMIC_ACQUIRE,
                                 __HIP_MEMORY_SCOPE_AGENT) < 32)
          __builtin_amdgcn_s_sleep(16);
      }
      __syncthreads();
      __threadfence();                     // acquire fence for all waves

      const size_t baseA = (size_t)b * C_ * N_ + (size_t)gi * BM * N_;
      const size_t baseB = (size_t)b * C_ * N_ + (size_t)gj * BM * N_;
      const unsigned char* gA = (selA ? ns : nt) + baseA;
      const unsigned char* gB = (selB ? ns : nt) + baseB;

      const int wr = wave >> 1, wc = wave & 1;   // 2x2 waves -> 64x64 each
      const int fr = lane & 15;                  // fragment row
      const int kg = lane >> 4;                  // k-group (32 fp8 bytes each)

      f32x4 acc[4][4];
      #pragma unroll
      for (int m = 0; m < 4; ++m)
        #pragma unroll
        for (int n = 0; n < 4; ++n)
          acc[m][n] = (f32x4)0.0f;

      for (int kt = 0; kt < N_ / BK; ++kt) {
        const int k0 = kt * BK;
        __syncthreads();                   // prior fragment reads done
        #pragma unroll
        for (int r = 0; r < 4; ++r) {
          const int chunk = r * 256 + tid;       // [0,1024)
          const int row = chunk >> 3, cb = (chunk & 7) * 16;
          __builtin_amdgcn_global_load_lds(
              (const __attribute__((address_space(1))) void*)(gA + (size_t)row * N_ + k0 + cb),
              (__attribute__((address_space(3))) void*)(As + chunk * 16), 16, 0, 0);
        }
        #pragma unroll
        for (int r = 0; r < 4; ++r) {
          const int chunk = r * 256 + tid;
          const int row = chunk >> 3, cb = (chunk & 7) * 16;
          __builtin_amdgcn_global_load_lds(
              (const __attribute__((address_space(1))) void*)(gB + (size_t)row * N_ + k0 + cb),
              (__attribute__((address_space(3))) void*)(Bs + chunk * 16), 16, 0, 0);
        }
        __syncthreads();                   // staging complete

        i32x8 av[4], bv[4];
        #pragma unroll
        for (int m = 0; m < 4; ++m)
          av[m] = *(const i32x8*)(As + (wr * 64 + m * 16 + fr) * BK + kg * 32);
        #pragma unroll
        for (int n = 0; n < 4; ++n)
          bv[n] = *(const i32x8*)(Bs + (wc * 64 + n * 16 + fr) * BK + kg * 32);
        #pragma unroll
        for (int m = 0; m < 4; ++m)
          #pragma unroll
          for (int n = 0; n < 4; ++n)
            acc[m][n] = __builtin_amdgcn_mfma_scale_f32_16x16x128_f8f6f4(
                av[m], bv[n], acc[m][n],
                0, 0,                 // cbsz/blgp = fp8(e4m3)
                0, 0x7F7F7F7F,        // scale_a = 1.0 (E8M0 127)
                0, 0x7F7F7F7F);       // scale_b = 1.0
      }

      // epilogue: weighted sum of squares (layout-independent)
      float p = 0.0f;
      #pragma unroll
      for (int m = 0; m < 4; ++m)
        #pragma unroll
        for (int n = 0; n < 4; ++n)
          #pragma unroll
          for (int j = 0; j < 4; ++j)
            p += acc[m][n][j] * acc[m][n][j];
      p *= wgt;
      p = wave_reduce(p);
      __syncthreads();                     // As/Bs dead -> red alias safe
      if (lane == 0) red[wave] = p;
      __syncthreads();
      if (tid == 0) {
        partials[gjob] = red[0] + red[1] + red[2] + red[3];
        __threadfence();                   // release partials
        atomicAdd(&ctrl[1], 1);
      }

    } else if (job == TOTAL_JOBS) {
      // ---------------- final reduce (exactly one block grabs this) --------
      if (tid == 0) {
        while (__hip_atomic_load(&ctrl[1], __ATOMIC_ACQUIRE,
                                 __HIP_MEMORY_SCOPE_AGENT) < NGRAM)
          __builtin_amdgcn_s_sleep(16);
      }
      __syncthreads();
      __threadfence();
      float v = 0.0f;
      for (int i = tid; i < NGRAM; i += 256)
        v += __hip_atomic_load(&partials[i], __ATOMIC_RELAXED,
                               __HIP_MEMORY_SCOPE_AGENT);
      v = wave_reduce(v);
      if (lane == 0) red[wave] = v;
      __syncthreads();
      if (tid == 0)   // 1/(B*C*C) * 2^-16 = 2^-40
        out[0] = (red[0] + red[1] + red[2] + red[3]) * (1.0f / 1099511627776.0f);
      break;
    } else {
      break;                               // queue drained
    }
  }
}

extern "C" void kernel_launch(void* const* d_in, const int* in_sizes, int n_in,
                              void* d_out, int out_size, void* d_ws, size_t ws_size,
                              hipStream_t stream) {
  const float* fm_s = (const float*)d_in[0];
  const float* fm_t = (const float*)d_in[1];
  float* out = (float*)d_out;

  const size_t fp8_elems = (size_t)B_ * C_ * N_;           // per tensor (bytes)
  unsigned char* nt = (unsigned char*)d_ws;
  unsigned char* ns = nt + fp8_elems;
  float* partials = (float*)((char*)d_ws + 2 * fp8_elems);
  int* ctrl = (int*)(partials + NGRAM);

  zero_ctrl<<<1, 128, 0, stream>>>(ctrl);
  fused_nst<<<NBLOCKS, 256, 0, stream>>>(fm_t, fm_s, nt, ns, partials, ctrl, out);
}

// Round 6
// 105.090 us; speedup vs baseline: 10.8355x; 10.8355x over previous
//
#include <hip/hip_runtime.h>
#include <hip/hip_bf16.h>

#define B_   64
#define C_   512
#define N_   1024
#define NROW (B_ * C_)        // 32768 rows per tensor
#define BM   128
#define BK   128              // fp8 K-tile (one 16x16x128 MFMA deep)
#define NJOBS 36              // 10 tt + 10 ss + 16 ts tiles per batch
#define NBLK (B_ * NJOBS)     // 2304 blocks

typedef __attribute__((ext_vector_type(8))) int   i32x8;
typedef __attribute__((ext_vector_type(4))) float f32x4;

__device__ __forceinline__ float wave_reduce(float v) {
  #pragma unroll
  for (int o = 32; o > 0; o >>= 1) v += __shfl_down(v, o, 64);
  return v;
}

// ---------------- Kernel 1: fused L2-normalize + (x16) fp8-e4m3 convert ----
// one WAVE per row of 1024 floats. NONTEMPORAL input loads: input has zero
// reuse inside or across replays; keeping it out of L2/L3 lets the stream
// run at pure-HBM rate instead of the slower mixed L3-intercept path, and
// leaves L3 free for the fp8 output that gram re-reads.
__global__ __launch_bounds__(256) void rownorm_fp8(
    const float* __restrict__ fmt, const float* __restrict__ fms,
    unsigned char* __restrict__ nt, unsigned char* __restrict__ ns) {
  const int gw   = blockIdx.x * 4 + (threadIdx.x >> 6);  // global wave = row id
  const int lane = threadIdx.x & 63;
  const int arr  = gw >> 15;            // 0 -> t, 1 -> s
  const int row  = gw & (NROW - 1);
  const float* src = (arr ? fms : fmt) + (size_t)row * N_;
  unsigned char* dst = (arr ? ns : nt) + (size_t)row * N_;

  f32x4 v[4];
  #pragma unroll
  for (int j = 0; j < 4; ++j)
    v[j] = __builtin_nontemporal_load((const f32x4*)(src + j * 256 + lane * 4));

  float ss = 0.0f;
  #pragma unroll
  for (int j = 0; j < 4; ++j)
    ss += v[j][0] * v[j][0] + v[j][1] * v[j][1]
        + v[j][2] * v[j][2] + v[j][3] * v[j][3];
  #pragma unroll
  for (int o = 1; o < 64; o <<= 1) ss += __shfl_xor(ss, o, 64);

  // x16 scale keeps values in e4m3 normal range; removed exactly (2^-40 total)
  const float inv = 16.0f / fmaxf(sqrtf(ss), 1e-12f);
  #pragma unroll
  for (int j = 0; j < 4; ++j) {
    int p = __builtin_amdgcn_cvt_pk_fp8_f32(v[j][0] * inv, v[j][1] * inv, 0, false);
    p = __builtin_amdgcn_cvt_pk_fp8_f32(v[j][2] * inv, v[j][3] * inv, p, true);
    ((int*)(dst + j * 256))[lane] = p;
  }
}

// ---------------- Kernel 2: batched gram sum-of-squares (MX-fp8, K=128) ----
__global__ __launch_bounds__(256) void gram_kernel(
    const unsigned char* __restrict__ nt, const unsigned char* __restrict__ ns,
    float* __restrict__ partials)
{
  __shared__ __align__(64) unsigned char As[BM * BK];
  __shared__ __align__(64) unsigned char Bs[BM * BK];
  __shared__ float red[4];

  const int tid = threadIdx.x;
  const int orig = blockIdx.x;
  // bijective XCD swizzle: 2304 = 288 * 8 -> XCD x gets batches [x*8, x*8+8)
  const int lin = (orig & 7) * (NBLK / 8) + (orig >> 3);
  const int b = lin / NJOBS;
  const int job = lin - b * NJOBS;

  int gi, gj;
  float wgt;
  int selA, selB;                 // 0 = t, 1 = s
  if (job < 20) {
    const int idx = (job < 10) ? job : job - 10;
    int i = 0, t = idx;
    while (t >= 4 - i) { t -= 4 - i; ++i; }
    gi = i; gj = i + t;
    wgt = (gi == gj) ? 1.0f : 2.0f;
    selA = selB = (job < 10) ? 0 : 1;
  } else {
    const int idx = job - 20;
    gi = idx >> 2; gj = idx & 3;
    wgt = -2.0f;
    selA = 0; selB = 1;
  }

  const size_t baseA = (size_t)b * C_ * N_ + (size_t)gi * BM * N_;
  const size_t baseB = (size_t)b * C_ * N_ + (size_t)gj * BM * N_;
  const unsigned char* gA = (selA ? ns : nt) + baseA;
  const unsigned char* gB = (selB ? ns : nt) + baseB;

  const int lane = tid & 63;
  const int wave = tid >> 6;
  const int wr = wave >> 1, wc = wave & 1;   // 2x2 waves -> 64x64 each
  const int fr = lane & 15;                  // fragment row
  const int kg = lane >> 4;                  // k-group (32 fp8 bytes each)

  f32x4 acc[4][4];
  #pragma unroll
  for (int m = 0; m < 4; ++m)
    #pragma unroll
    for (int n = 0; n < 4; ++n)
      acc[m][n] = (f32x4)0.0f;

  for (int kt = 0; kt < N_ / BK; ++kt) {
    const int k0 = kt * BK;
    __syncthreads();   // previous fragment reads complete before overwrite
    // stage A tile: 128 rows x 128 fp8 bytes = 16 KB, 16B chunks
    #pragma unroll
    for (int r = 0; r < 4; ++r) {
      const int chunk = r * 256 + tid;          // [0,1024)
      const int row = chunk >> 3, cb = (chunk & 7) * 16;
      __builtin_amdgcn_global_load_lds(
          (const __attribute__((address_space(1))) void*)(gA + (size_t)row * N_ + k0 + cb),
          (__attribute__((address_space(3))) void*)(As + chunk * 16), 16, 0, 0);
    }
    #pragma unroll
    for (int r = 0; r < 4; ++r) {
      const int chunk = r * 256 + tid;
      const int row = chunk >> 3, cb = (chunk & 7) * 16;
      __builtin_amdgcn_global_load_lds(
          (const __attribute__((address_space(1))) void*)(gB + (size_t)row * N_ + k0 + cb),
          (__attribute__((address_space(3))) void*)(Bs + chunk * 16), 16, 0, 0);
    }
    __syncthreads();   // staging complete (compiler drains vmcnt before barrier)

    i32x8 av[4], bv[4];
    #pragma unroll
    for (int m = 0; m < 4; ++m)
      av[m] = *(const i32x8*)(As + (wr * 64 + m * 16 + fr) * BK + kg * 32);
    #pragma unroll
    for (int n = 0; n < 4; ++n)
      bv[n] = *(const i32x8*)(Bs + (wc * 64 + n * 16 + fr) * BK + kg * 32);
    #pragma unroll
    for (int m = 0; m < 4; ++m)
      #pragma unroll
      for (int n = 0; n < 4; ++n)
        acc[m][n] = __builtin_amdgcn_mfma_scale_f32_16x16x128_f8f6f4(
            av[m], bv[n], acc[m][n],
            0, 0,                 // cbsz = fp8(e4m3), blgp = fp8(e4m3)
            0, 0x7F7F7F7F,        // opsel_a, scale_a (E8M0 127 = 1.0 in all bytes)
            0, 0x7F7F7F7F);       // opsel_b, scale_b
  }

  // epilogue: weighted sum of squares (layout-independent)
  float p = 0.0f;
  #pragma unroll
  for (int m = 0; m < 4; ++m)
    #pragma unroll
    for (int n = 0; n < 4; ++n)
      #pragma unroll
      for (int j = 0; j < 4; ++j)
        p += acc[m][n][j] * acc[m][n][j];
  p *= wgt;
  p = wave_reduce(p);
  if (lane == 0) red[wave] = p;
  __syncthreads();
  if (tid == 0) partials[orig] = red[0] + red[1] + red[2] + red[3];
}

// ---------------- Kernel 3: final deterministic reduce ----------------------
// factor 2^-40 = 1/(B*C*C) * 2^-16 (the x16 input scaling, squared twice)
__global__ __launch_bounds__(256) void reduce_partials(
    const float* __restrict__ partials, float* __restrict__ out) {
  float v = 0.0f;
  for (int i = threadIdx.x; i < NBLK; i += 256) v += partials[i];
  v = wave_reduce(v);
  __shared__ float red[4];
  const int lane = threadIdx.x & 63, w = threadIdx.x >> 6;
  if (lane == 0) red[w] = v;
  __syncthreads();
  if (threadIdx.x == 0)
    out[0] = (red[0] + red[1] + red[2] + red[3]) * (1.0f / 1099511627776.0f);
}

extern "C" void kernel_launch(void* const* d_in, const int* in_sizes, int n_in,
                              void* d_out, int out_size, void* d_ws, size_t ws_size,
                              hipStream_t stream) {
  const float* fm_s = (const float*)d_in[0];
  const float* fm_t = (const float*)d_in[1];
  float* out = (float*)d_out;

  const size_t fp8_elems = (size_t)B_ * C_ * N_;           // per tensor (bytes)
  unsigned char* nt = (unsigned char*)d_ws;
  unsigned char* ns = nt + fp8_elems;
  float* partials = (float*)((char*)d_ws + 2 * fp8_elems);

  rownorm_fp8<<<2 * NROW / 4, 256, 0, stream>>>(fm_t, fm_s, nt, ns);
  gram_kernel<<<NBLK, 256, 0, stream>>>(nt, ns, partials);
  reduce_partials<<<1, 256, 0, stream>>>(partials, out);
}

// Round 7
// 104.978 us; speedup vs baseline: 10.8471x; 1.0011x over previous
//
#include <hip/hip_runtime.h>
#include <hip/hip_bf16.h>

#define B_   64
#define C_   512
#define N_   1024
#define NROW (B_ * C_)        // 32768 rows per tensor
#define BM   128
#define BK   128              // fp8 K-tile (one 16x16x128 MFMA deep)
#define NJOBS 36              // 10 tt + 10 ss + 16 ts tiles per batch
#define NBLK (B_ * NJOBS)     // 2304 blocks

typedef __attribute__((ext_vector_type(8))) int   i32x8;
typedef __attribute__((ext_vector_type(4))) float f32x4;

__device__ __forceinline__ float wave_reduce(float v) {
  #pragma unroll
  for (int o = 32; o > 0; o >>= 1) v += __shfl_down(v, o, 64);
  return v;
}

// ---------------- Kernel 1: fused L2-normalize + (x16) fp8-e4m3 convert ----
// one WAVE per row of 1024 floats. Regular (cacheable) input loads so the
// 268 MB input can live in Infinity Cache; NONTEMPORAL stores for the fp8
// output so the 64 MB output stream does NOT allocate in L3 and evict the
// input mid-pass (output-pollution hypothesis for the ~50% L3 hit rate).
__global__ __launch_bounds__(256) void rownorm_fp8(
    const float* __restrict__ fmt, const float* __restrict__ fms,
    unsigned char* __restrict__ nt, unsigned char* __restrict__ ns) {
  const int gw   = blockIdx.x * 4 + (threadIdx.x >> 6);  // global wave = row id
  const int lane = threadIdx.x & 63;
  const int arr  = gw >> 15;            // 0 -> t, 1 -> s
  const int row  = gw & (NROW - 1);
  const float* src = (arr ? fms : fmt) + (size_t)row * N_;
  unsigned char* dst = (arr ? ns : nt) + (size_t)row * N_;

  f32x4 v[4];
  #pragma unroll
  for (int j = 0; j < 4; ++j)
    v[j] = *(const f32x4*)(src + j * 256 + lane * 4);

  float ss = 0.0f;
  #pragma unroll
  for (int j = 0; j < 4; ++j)
    ss += v[j][0] * v[j][0] + v[j][1] * v[j][1]
        + v[j][2] * v[j][2] + v[j][3] * v[j][3];
  #pragma unroll
  for (int o = 1; o < 64; o <<= 1) ss += __shfl_xor(ss, o, 64);

  // x16 scale keeps values in e4m3 normal range; removed exactly (2^-40 total)
  const float inv = 16.0f / fmaxf(sqrtf(ss), 1e-12f);
  #pragma unroll
  for (int j = 0; j < 4; ++j) {
    int p = __builtin_amdgcn_cvt_pk_fp8_f32(v[j][0] * inv, v[j][1] * inv, 0, false);
    p = __builtin_amdgcn_cvt_pk_fp8_f32(v[j][2] * inv, v[j][3] * inv, p, true);
    __builtin_nontemporal_store(p, ((int*)(dst + j * 256)) + lane);
  }
}

// ---------------- Kernel 2: batched gram sum-of-squares (MX-fp8, K=128) ----
__global__ __launch_bounds__(256) void gram_kernel(
    const unsigned char* __restrict__ nt, const unsigned char* __restrict__ ns,
    float* __restrict__ partials)
{
  __shared__ __align__(64) unsigned char As[BM * BK];
  __shared__ __align__(64) unsigned char Bs[BM * BK];
  __shared__ float red[4];

  const int tid = threadIdx.x;
  const int orig = blockIdx.x;
  // bijective XCD swizzle: 2304 = 288 * 8 -> XCD x gets batches [x*8, x*8+8)
  const int lin = (orig & 7) * (NBLK / 8) + (orig >> 3);
  const int b = lin / NJOBS;
  const int job = lin - b * NJOBS;

  int gi, gj;
  float wgt;
  int selA, selB;                 // 0 = t, 1 = s
  if (job < 20) {
    const int idx = (job < 10) ? job : job - 10;
    int i = 0, t = idx;
    while (t >= 4 - i) { t -= 4 - i; ++i; }
    gi = i; gj = i + t;
    wgt = (gi == gj) ? 1.0f : 2.0f;
    selA = selB = (job < 10) ? 0 : 1;
  } else {
    const int idx = job - 20;
    gi = idx >> 2; gj = idx & 3;
    wgt = -2.0f;
    selA = 0; selB = 1;
  }

  const size_t baseA = (size_t)b * C_ * N_ + (size_t)gi * BM * N_;
  const size_t baseB = (size_t)b * C_ * N_ + (size_t)gj * BM * N_;
  const unsigned char* gA = (selA ? ns : nt) + baseA;
  const unsigned char* gB = (selB ? ns : nt) + baseB;

  const int lane = tid & 63;
  const int wave = tid >> 6;
  const int wr = wave >> 1, wc = wave & 1;   // 2x2 waves -> 64x64 each
  const int fr = lane & 15;                  // fragment row
  const int kg = lane >> 4;                  // k-group (32 fp8 bytes each)

  f32x4 acc[4][4];
  #pragma unroll
  for (int m = 0; m < 4; ++m)
    #pragma unroll
    for (int n = 0; n < 4; ++n)
      acc[m][n] = (f32x4)0.0f;

  for (int kt = 0; kt < N_ / BK; ++kt) {
    const int k0 = kt * BK;
    __syncthreads();   // previous fragment reads complete before overwrite
    // stage A tile: 128 rows x 128 fp8 bytes = 16 KB, 16B chunks
    #pragma unroll
    for (int r = 0; r < 4; ++r) {
      const int chunk = r * 256 + tid;          // [0,1024)
      const int row = chunk >> 3, cb = (chunk & 7) * 16;
      __builtin_amdgcn_global_load_lds(
          (const __attribute__((address_space(1))) void*)(gA + (size_t)row * N_ + k0 + cb),
          (__attribute__((address_space(3))) void*)(As + chunk * 16), 16, 0, 0);
    }
    #pragma unroll
    for (int r = 0; r < 4; ++r) {
      const int chunk = r * 256 + tid;
      const int row = chunk >> 3, cb = (chunk & 7) * 16;
      __builtin_amdgcn_global_load_lds(
          (const __attribute__((address_space(1))) void*)(gB + (size_t)row * N_ + k0 + cb),
          (__attribute__((address_space(3))) void*)(Bs + chunk * 16), 16, 0, 0);
    }
    __syncthreads();   // staging complete (compiler drains vmcnt before barrier)

    i32x8 av[4], bv[4];
    #pragma unroll
    for (int m = 0; m < 4; ++m)
      av[m] = *(const i32x8*)(As + (wr * 64 + m * 16 + fr) * BK + kg * 32);
    #pragma unroll
    for (int n = 0; n < 4; ++n)
      bv[n] = *(const i32x8*)(Bs + (wc * 64 + n * 16 + fr) * BK + kg * 32);
    #pragma unroll
    for (int m = 0; m < 4; ++m)
      #pragma unroll
      for (int n = 0; n < 4; ++n)
        acc[m][n] = __builtin_amdgcn_mfma_scale_f32_16x16x128_f8f6f4(
            av[m], bv[n], acc[m][n],
            0, 0,                 // cbsz = fp8(e4m3), blgp = fp8(e4m3)
            0, 0x7F7F7F7F,        // opsel_a, scale_a (E8M0 127 = 1.0 in all bytes)
            0, 0x7F7F7F7F);       // opsel_b, scale_b
  }

  // epilogue: weighted sum of squares (layout-independent)
  float p = 0.0f;
  #pragma unroll
  for (int m = 0; m < 4; ++m)
    #pragma unroll
    for (int n = 0; n < 4; ++n)
      #pragma unroll
      for (int j = 0; j < 4; ++j)
        p += acc[m][n][j] * acc[m][n][j];
  p *= wgt;
  p = wave_reduce(p);
  if (lane == 0) red[wave] = p;
  __syncthreads();
  if (tid == 0) partials[orig] = red[0] + red[1] + red[2] + red[3];
}

// ---------------- Kernel 3: final deterministic reduce ----------------------
// factor 2^-40 = 1/(B*C*C) * 2^-16 (the x16 input scaling, squared twice)
__global__ __launch_bounds__(256) void reduce_partials(
    const float* __restrict__ partials, float* __restrict__ out) {
  float v = 0.0f;
  for (int i = threadIdx.x; i < NBLK; i += 256) v += partials[i];
  v = wave_reduce(v);
  __shared__ float red[4];
  const int lane = threadIdx.x & 63, w = threadIdx.x >> 6;
  if (lane == 0) red[w] = v;
  __syncthreads();
  if (threadIdx.x == 0)
    out[0] = (red[0] + red[1] + red[2] + red[3]) * (1.0f / 1099511627776.0f);
}

extern "C" void kernel_launch(void* const* d_in, const int* in_sizes, int n_in,
                              void* d_out, int out_size, void* d_ws, size_t ws_size,
                              hipStream_t stream) {
  const float* fm_s = (const float*)d_in[0];
  const float* fm_t = (const float*)d_in[1];
  float* out = (float*)d_out;

  const size_t fp8_elems = (size_t)B_ * C_ * N_;           // per tensor (bytes)
  unsigned char* nt = (unsigned char*)d_ws;
  unsigned char* ns = nt + fp8_elems;
  float* partials = (float*)((char*)d_ws + 2 * fp8_elems);

  rownorm_fp8<<<2 * NROW / 4, 256, 0, stream>>>(fm_t, fm_s, nt, ns);
  gram_kernel<<<NBLK, 256, 0, stream>>>(nt, ns, partials);
  reduce_partials<<<1, 256, 0, stream>>>(partials, out);
}